// Round 10
// baseline (427.694 us; speedup 1.0000x reference)
//
#include <hip/hip_runtime.h>
#include <math.h>

static inline int cdiv(long long a, int b){ return (int)((a + b - 1) / b); }
#define DEVINL __device__ __forceinline__

DEVINL float4 relu4(const float* a){
  return make_float4(fmaxf(a[0],0.f), fmaxf(a[1],0.f), fmaxf(a[2],0.f), fmaxf(a[3],0.f));
}

DEVINL void load32(float* fv, const float* __restrict__ p){
#pragma unroll
  for (int q = 0; q < 8; ++q){
    float4 v = ((const float4*)p)[q];
    fv[4*q]=v.x; fv[4*q+1]=v.y; fv[4*q+2]=v.z; fv[4*q+3]=v.w;
  }
}
DEVINL void load8(float* fv, const float* __restrict__ p){
#pragma unroll
  for (int q = 0; q < 2; ++q){
    float4 v = ((const float4*)p)[q];
    fv[4*q]=v.x; fv[4*q+1]=v.y; fv[4*q+2]=v.z; fv[4*q+3]=v.w;
  }
}

// tap index for sibling pair: d = o' - o componentwise; k = (dx+1)*9+(dy+1)*3+(dz+1)
DEVINL int sib_k(int o, int op){
  return 13 + 9*(((op>>2)&1) - ((o>>2)&1))
            + 3*(((op>>1)&1) - ((o>>1)&1))
            +   ((op&1) - (o&1));
}

// ---------- remainder list build: cross-parent valid neighbors only ----------
__global__ void k_rinit(int* __restrict__ cnt, int n){
  int i = blockIdx.x*blockDim.x + threadIdx.x;
  if (i < n) cnt[i] = 0;
}

__global__ void k_rbuild(const int* __restrict__ nin, const int* __restrict__ nout,
                         int* __restrict__ cnt, int* __restrict__ rem, int P, int N){
  int p = blockIdx.x*blockDim.x + threadIdx.x;
  if (p >= 27*P) return;
  int oi = nout[p];
  if (oi >= N) return;
  int j = nin[p];
  if ((oi >> 3) == (j >> 3)) return;
  int k = p / P;
  int pos = atomicAdd(&cnt[oi], 1);
  rem[(size_t)oi*20 + pos] = (j << 5) | k;
}

// ---------- up (r9): R=4 parents/thread, wave=kk (uniform); grid Nn/32 ----------
__global__ __launch_bounds__(512) void k_up(const float* __restrict__ x,
    const float* __restrict__ Wup, const float* __restrict__ bup,
    float* __restrict__ f, int Nn){
  __shared__ float Ws[8*64*32];
  int t = threadIdx.x;
  for (int m = t; m < 4096; m += 512)
    ((float4*)Ws)[m] = ((const float4*)Wup)[m];
  __syncthreads();
  int kk = t >> 6;
  int lane = t & 63, nq = lane >> 3, cg = lane & 7;
  int n0 = blockIdx.x*32 + nq*4;
  int c0 = cg*4;
  const float* wk = Ws + kk*2048 + c0;
  float4 b4 = *(const float4*)(bup + c0);
  float acc[4][4];
#pragma unroll
  for (int i = 0; i < 4; ++i){ acc[i][0]=b4.x; acc[i][1]=b4.y; acc[i][2]=b4.z; acc[i][3]=b4.w; }
#pragma unroll
  for (int h = 0; h < 8; ++h){
    float fv[4][8];
#pragma unroll
    for (int i = 0; i < 4; ++i){
      float4 v0 = ((const float4*)(x + (size_t)(n0+i)*64))[h*2+0];
      float4 v1 = ((const float4*)(x + (size_t)(n0+i)*64))[h*2+1];
      fv[i][0]=v0.x; fv[i][1]=v0.y; fv[i][2]=v0.z; fv[i][3]=v0.w;
      fv[i][4]=v1.x; fv[i][5]=v1.y; fv[i][6]=v1.z; fv[i][7]=v1.w;
    }
#pragma unroll
    for (int cc = 0; cc < 8; ++cc){
      float4 w = *(const float4*)(wk + (h*8+cc)*32);
#pragma unroll
      for (int i = 0; i < 4; ++i){
        acc[i][0]=fmaf(fv[i][cc],w.x,acc[i][0]); acc[i][1]=fmaf(fv[i][cc],w.y,acc[i][1]);
        acc[i][2]=fmaf(fv[i][cc],w.z,acc[i][2]); acc[i][3]=fmaf(fv[i][cc],w.w,acc[i][3]);
      }
    }
  }
#pragma unroll
  for (int i = 0; i < 4; ++i)
    *(float4*)(f + ((size_t)(n0+i)*8 + kk)*32 + c0) = relu4(acc[i]);
}

// ---------- conv1: sibling-static, wave=o, R=2 parents x 4 outs, y-half ----------
// block 512 = 8 waves(=o) x [16 parent-pairs x 4 cg]; covers 32 parents x 16 outs.
// grid (Nn/32, 2) = 512 blocks -> 2 blocks/CU, 16 waves/CU.
__global__ __launch_bounds__(512) void k_conv1(const float* __restrict__ fin,
    const float* __restrict__ Wg, const float* __restrict__ bg,
    const int* __restrict__ cnt, const int* __restrict__ rem,
    float* __restrict__ fout, int N){
  __shared__ float Ws[27*512];            // [kk][cc][16], 55.3 KB
  const int y = blockIdx.y;
  int t = threadIdx.x;
  for (int m = t; m < 3456; m += 512){
    int kk = m >> 7, r = m & 127, cc = r >> 2, c4 = r & 3;
    *(float4*)&Ws[kk*512 + cc*16 + c4*4] =
      *(const float4*)&Wg[((size_t)(kk*32+cc))*32 + y*16 + c4*4];
  }
  __syncthreads();
  int o = t >> 6, lane = t & 63;
  int pq = lane >> 2, cg = lane & 3;
  int pbase = blockIdx.x*32 + pq*2;       // 2 parents
  int c0 = cg*4;
  float4 b4 = *(const float4*)(bg + y*16 + c0);
  float acc[2][4];
#pragma unroll
  for (int i = 0; i < 2; ++i){ acc[i][0]=b4.x; acc[i][1]=b4.y; acc[i][2]=b4.z; acc[i][3]=b4.w; }
#pragma unroll 1
  for (int op = 0; op < 8; ++op){
    int kk = sib_k(o, op);                // wave-uniform
    const float* wk = Ws + kk*512 + c0;
    const float4* r0 = (const float4*)(fin + ((size_t)((pbase+0)*8 + op))*32);
    const float4* r1 = (const float4*)(fin + ((size_t)((pbase+1)*8 + op))*32);
#pragma unroll
    for (int h = 0; h < 4; ++h){          // 8-cc chunks
      float fv[2][8];
      float4 v0 = r0[h*2+0], v1 = r0[h*2+1];
      float4 u0 = r1[h*2+0], u1 = r1[h*2+1];
      fv[0][0]=v0.x; fv[0][1]=v0.y; fv[0][2]=v0.z; fv[0][3]=v0.w;
      fv[0][4]=v1.x; fv[0][5]=v1.y; fv[0][6]=v1.z; fv[0][7]=v1.w;
      fv[1][0]=u0.x; fv[1][1]=u0.y; fv[1][2]=u0.z; fv[1][3]=u0.w;
      fv[1][4]=u1.x; fv[1][5]=u1.y; fv[1][6]=u1.z; fv[1][7]=u1.w;
#pragma unroll
      for (int cc = 0; cc < 8; ++cc){
        float4 w = *(const float4*)(wk + (h*8+cc)*16);
#pragma unroll
        for (int i = 0; i < 2; ++i){
          acc[i][0]=fmaf(fv[i][cc],w.x,acc[i][0]); acc[i][1]=fmaf(fv[i][cc],w.y,acc[i][1]);
          acc[i][2]=fmaf(fv[i][cc],w.z,acc[i][2]); acc[i][3]=fmaf(fv[i][cc],w.w,acc[i][3]);
        }
      }
    }
  }
  // remainder + store per row
#pragma unroll 1
  for (int i = 0; i < 2; ++i){
    int row = (pbase+i)*8 + o;
    int nrm = cnt[row];
    for (int s = 0; s < nrm; ++s){
      int e = rem[(size_t)row*20 + s];
      int kk = e & 31, jr = e >> 5;
      const float* fr = fin + (size_t)jr*32;
      const float* wk = Ws + kk*512 + c0;
#pragma unroll
      for (int cc = 0; cc < 32; ++cc){
        float4 w = *(const float4*)(wk + cc*16);
        float fx = fr[cc];
        acc[i][0]=fmaf(fx,w.x,acc[i][0]); acc[i][1]=fmaf(fx,w.y,acc[i][1]);
        acc[i][2]=fmaf(fx,w.z,acc[i][2]); acc[i][3]=fmaf(fx,w.w,acc[i][3]);
      }
    }
    *(float4*)(fout + (size_t)row*32 + y*16 + c0) = relu4(acc[i]);
  }
}

// ---------- blk_a: a8 = relu(sconv32->8+b00); b8 = relu(f@W10+b10) ----------
// block 512 = 8 waves(=o) x [16 parents x 4 cg(2 outs)]; covers 16 parents x 8 outs.
// grid Nn/16 = 512 blocks -> 2/CU, 16 waves/CU. Weight reads = float2 (b64).
__global__ __launch_bounds__(512) void k_blk_a(const float* __restrict__ fO,
    const float* __restrict__ W00, const float* __restrict__ b00,
    const float* __restrict__ W10, const float* __restrict__ b10,
    const int* __restrict__ cnt, const int* __restrict__ rem,
    float* __restrict__ a8, float* __restrict__ b8, int N){
  __shared__ float Ws[27*256 + 256];
  int t = threadIdx.x;
  for (int m = t; m < 1728; m += 512)
    ((float4*)Ws)[m] = ((const float4*)W00)[m];    // [kk][cc][8] native layout
  if (t < 64) *(float4*)&Ws[6912 + t*4] = ((const float4*)W10)[t];
  __syncthreads();
  int o = t >> 6, lane = t & 63;
  int p = lane >> 2, cg = lane & 3;
  int parent = blockIdx.x*16 + p;
  int base = parent*8, row = base + o;
  int c0 = cg*2;
  float acc[2] = {b00[c0], b00[c0+1]};
  float fv[32];
#pragma unroll 1
  for (int op = 0; op < 8; ++op){
    int kk = sib_k(o, op);                // wave-uniform
    load32(fv, fO + (size_t)(base+op)*32);
    const float* wk = Ws + kk*256 + c0;
#pragma unroll
    for (int cc = 0; cc < 32; ++cc){
      float2 w = *(const float2*)(wk + cc*8);
      acc[0]=fmaf(fv[cc],w.x,acc[0]); acc[1]=fmaf(fv[cc],w.y,acc[1]);
    }
  }
  int nrm = cnt[row];
  for (int s = 0; s < nrm; ++s){
    int e = rem[(size_t)row*20 + s];
    int kk = e & 31, j = e >> 5;
    load32(fv, fO + (size_t)j*32);
    const float* wk = Ws + kk*256 + c0;
#pragma unroll
    for (int cc = 0; cc < 32; ++cc){
      float2 w = *(const float2*)(wk + cc*8);
      acc[0]=fmaf(fv[cc],w.x,acc[0]); acc[1]=fmaf(fv[cc],w.y,acc[1]);
    }
  }
  *(float2*)(a8 + (size_t)row*8 + c0) = make_float2(fmaxf(acc[0],0.f), fmaxf(acc[1],0.f));
  // dense branch on own row
  load32(fv, fO + (size_t)row*32);
  float accb[2] = {b10[c0], b10[c0+1]};
#pragma unroll
  for (int cc = 0; cc < 32; ++cc){
    float2 w = *(const float2*)(Ws + 6912 + cc*8 + c0);
    accb[0]=fmaf(fv[cc],w.x,accb[0]); accb[1]=fmaf(fv[cc],w.y,accb[1]);
  }
  *(float2*)(b8 + (size_t)row*8 + c0) = make_float2(fmaxf(accb[0],0.f), fmaxf(accb[1],0.f));
}

// ---------- blk_b (r6): fout[:,0:16] += sconv8->16(a8)+b01 ;
//            fout[:,16:32] += relu(sconv8->8(b8)+b11)@W12+b12 ----------
// block 512 = 8 waves(=o) x [16 parents x 4 cg]; grid N/128 = 512
__global__ __launch_bounds__(512) void k_blk_b(const float* __restrict__ a8,
    const float* __restrict__ b8,
    const float* __restrict__ W01, const float* __restrict__ b01,
    const float* __restrict__ W11, const float* __restrict__ b11,
    const float* __restrict__ W12, const float* __restrict__ b12,
    const int* __restrict__ cnt, const int* __restrict__ rem,
    float* __restrict__ fout, int N){
  __shared__ float Ws[27*128 + 27*64 + 128];   // 3456 + 1728 + 128
  int t = threadIdx.x;
  for (int m = t; m < 864; m += 512)
    ((float4*)Ws)[m] = ((const float4*)W01)[m];
  for (int m = t; m < 432; m += 512)
    ((float4*)(Ws + 3456))[m] = ((const float4*)W11)[m];
  if (t < 32) *(float4*)&Ws[5184 + t*4] = ((const float4*)W12)[t];
  __syncthreads();
  int o = t >> 6, lane = t & 63, p = lane >> 2, cg = lane & 3;
  int base = blockIdx.x*128 + p*8;
  int row = base + o, c0 = cg*4;
  float4 b4 = *(const float4*)(b01 + c0);
  float acc0[4] = {b4.x,b4.y,b4.z,b4.w};
  float t8[8];
#pragma unroll
  for (int c = 0; c < 8; ++c) t8[c] = b11[c];
  float av[8], bv[8];
#pragma unroll
  for (int op = 0; op < 8; ++op){
    int kk = sib_k(o, op);
    load8(av, a8 + (size_t)(base+op)*8);
    load8(bv, b8 + (size_t)(base+op)*8);
    const float* w01k = Ws + kk*128 + c0;
    const float* w11k = Ws + 3456 + kk*64;
#pragma unroll
    for (int cc = 0; cc < 8; ++cc){
      float4 w = *(const float4*)(w01k + cc*16);
      acc0[0]=fmaf(av[cc],w.x,acc0[0]); acc0[1]=fmaf(av[cc],w.y,acc0[1]);
      acc0[2]=fmaf(av[cc],w.z,acc0[2]); acc0[3]=fmaf(av[cc],w.w,acc0[3]);
      float4 u0 = *(const float4*)(w11k + cc*8);
      float4 u1 = *(const float4*)(w11k + cc*8 + 4);
      t8[0]=fmaf(bv[cc],u0.x,t8[0]); t8[1]=fmaf(bv[cc],u0.y,t8[1]);
      t8[2]=fmaf(bv[cc],u0.z,t8[2]); t8[3]=fmaf(bv[cc],u0.w,t8[3]);
      t8[4]=fmaf(bv[cc],u1.x,t8[4]); t8[5]=fmaf(bv[cc],u1.y,t8[5]);
      t8[6]=fmaf(bv[cc],u1.z,t8[6]); t8[7]=fmaf(bv[cc],u1.w,t8[7]);
    }
  }
  int nrm = cnt[row];
  for (int s = 0; s < nrm; ++s){
    int e = rem[(size_t)row*20 + s];
    int kk = e & 31, j = e >> 5;
    load8(av, a8 + (size_t)j*8);
    load8(bv, b8 + (size_t)j*8);
    const float* w01k = Ws + kk*128 + c0;
    const float* w11k = Ws + 3456 + kk*64;
#pragma unroll
    for (int cc = 0; cc < 8; ++cc){
      float4 w = *(const float4*)(w01k + cc*16);
      acc0[0]=fmaf(av[cc],w.x,acc0[0]); acc0[1]=fmaf(av[cc],w.y,acc0[1]);
      acc0[2]=fmaf(av[cc],w.z,acc0[2]); acc0[3]=fmaf(av[cc],w.w,acc0[3]);
      float4 u0 = *(const float4*)(w11k + cc*8);
      float4 u1 = *(const float4*)(w11k + cc*8 + 4);
      t8[0]=fmaf(bv[cc],u0.x,t8[0]); t8[1]=fmaf(bv[cc],u0.y,t8[1]);
      t8[2]=fmaf(bv[cc],u0.z,t8[2]); t8[3]=fmaf(bv[cc],u0.w,t8[3]);
      t8[4]=fmaf(bv[cc],u1.x,t8[4]); t8[5]=fmaf(bv[cc],u1.y,t8[5]);
      t8[6]=fmaf(bv[cc],u1.z,t8[6]); t8[7]=fmaf(bv[cc],u1.w,t8[7]);
    }
  }
#pragma unroll
  for (int c = 0; c < 8; ++c) t8[c] = fmaxf(t8[c], 0.f);
  float4 d4 = *(const float4*)(b12 + c0);
  float acc1[4] = {d4.x,d4.y,d4.z,d4.w};
#pragma unroll
  for (int cc = 0; cc < 8; ++cc){
    float4 w = *(const float4*)(Ws + 5184 + cc*16 + c0);
    acc1[0]=fmaf(t8[cc],w.x,acc1[0]); acc1[1]=fmaf(t8[cc],w.y,acc1[1]);
    acc1[2]=fmaf(t8[cc],w.z,acc1[2]); acc1[3]=fmaf(t8[cc],w.w,acc1[3]);
  }
  float4* o0 = (float4*)(fout + (size_t)row*32 + c0);
  float4* o1 = (float4*)(fout + (size_t)row*32 + 16 + c0);
  float4 v0 = *o0, v1 = *o1;
  v0.x+=acc0[0]; v0.y+=acc0[1]; v0.z+=acc0[2]; v0.w+=acc0[3];
  v1.x+=acc1[0]; v1.y+=acc1[1]; v1.z+=acc1[2]; v1.w+=acc1[3];
  *o0 = v0; *o1 = v1;
}

// ---------- cls: 32->1 conv; c-quarter split + shuffle reduce ----------
// block 256 = 4 waves(o = by*4+w) x [16 parents x 4 q]; grid (Nn/16, 2) = 1024 blocks
__global__ __launch_bounds__(256) void k_cls(const float* __restrict__ fO,
    const float* __restrict__ Wc, const float* __restrict__ bc,
    const int* __restrict__ cnt, const int* __restrict__ rem,
    float* __restrict__ cls, int N){
  __shared__ float Ws[27*32];
  int t = threadIdx.x;
  if (t < 216) ((float4*)Ws)[t] = ((const float4*)Wc)[t];
  __syncthreads();
  int o = blockIdx.y*4 + (t >> 6);
  int lane = t & 63, p = lane >> 2, q = lane & 3;
  int base = (blockIdx.x*16 + p)*8;
  int row = base + o;
  float acc = 0.f;
#pragma unroll 1
  for (int op = 0; op < 8; ++op){
    int kk = sib_k(o, op);
    const float4* fp = (const float4*)(fO + (size_t)(base+op)*32 + q*8);
    float4 v0 = fp[0], v1 = fp[1];
    const float4* wp = (const float4*)(Ws + kk*32 + q*8);
    float4 w0 = wp[0], w1 = wp[1];
    acc = fmaf(v0.x,w0.x,acc); acc = fmaf(v0.y,w0.y,acc);
    acc = fmaf(v0.z,w0.z,acc); acc = fmaf(v0.w,w0.w,acc);
    acc = fmaf(v1.x,w1.x,acc); acc = fmaf(v1.y,w1.y,acc);
    acc = fmaf(v1.z,w1.z,acc); acc = fmaf(v1.w,w1.w,acc);
  }
  int nrm = cnt[row];
  for (int s = 0; s < nrm; ++s){
    int e = rem[(size_t)row*20 + s];
    int kk = e & 31, j = e >> 5;
    const float4* fp = (const float4*)(fO + (size_t)j*32 + q*8);
    float4 v0 = fp[0], v1 = fp[1];
    const float4* wp = (const float4*)(Ws + kk*32 + q*8);
    float4 w0 = wp[0], w1 = wp[1];
    acc = fmaf(v0.x,w0.x,acc); acc = fmaf(v0.y,w0.y,acc);
    acc = fmaf(v0.z,w0.z,acc); acc = fmaf(v0.w,w0.w,acc);
    acc = fmaf(v1.x,w1.x,acc); acc = fmaf(v1.y,w1.y,acc);
    acc = fmaf(v1.z,w1.z,acc); acc = fmaf(v1.w,w1.w,acc);
  }
  acc += __shfl_xor(acc, 1);
  acc += __shfl_xor(acc, 2);
  if (q == 0) cls[row] = acc + bc[0];
}

// ---------- max/argmax (first-index tie-break) ----------
__global__ void k_reduce1(const float* __restrict__ s, float* __restrict__ pmax,
                          int* __restrict__ pidx, int n){
  __shared__ float sm[256]; __shared__ int si[256];
  int t = threadIdx.x;
  float v = -INFINITY; int vi = 0x7fffffff;
  for (int j = blockIdx.x*256 + t; j < n; j += gridDim.x*256){
    float w = s[j];
    if (w > v){ v = w; vi = j; }
  }
  sm[t] = v; si[t] = vi; __syncthreads();
  for (int o = 128; o > 0; o >>= 1){
    if (t < o){
      if (sm[t+o] > sm[t] || (sm[t+o] == sm[t] && si[t+o] < si[t])){ sm[t]=sm[t+o]; si[t]=si[t+o]; }
    }
    __syncthreads();
  }
  if (t == 0){ pmax[blockIdx.x] = sm[0]; pidx[blockIdx.x] = si[0]; }
}

__global__ void k_reduce2(const float* __restrict__ pmax, const int* __restrict__ pidx,
                          float* __restrict__ g, int nb){
  __shared__ float sm[256]; __shared__ int si[256];
  int t = threadIdx.x;
  sm[t] = (t < nb) ? pmax[t] : -INFINITY;
  si[t] = (t < nb) ? pidx[t] : 0x7fffffff;
  __syncthreads();
  for (int o = 128; o > 0; o >>= 1){
    if (t < o){
      if (sm[t+o] > sm[t] || (sm[t+o] == sm[t] && si[t+o] < si[t])){ sm[t]=sm[t+o]; si[t]=si[t+o]; }
    }
    __syncthreads();
  }
  if (t == 0){ g[0] = sm[0]; ((int*)g)[1] = si[0]; }
}

// ---------- finalize ----------
__global__ void k_final(const float* __restrict__ out, const float* __restrict__ cls,
                        const int* __restrict__ target, const float* __restrict__ g,
                        float* __restrict__ dout, int n_out){
  int idx = blockIdx.x*blockDim.x + threadIdx.x;
  if (idx >= n_out*32) return;
  int row = idx >> 5, c = idx & 31;
  float s = cls[row];
  bool keep = s > 0.f;
  if (g[0] < 0.f) keep = keep || (row == ((const int*)g)[1]);
  float km = keep ? 1.f : 0.f;
  dout[idx] = out[idx] * km;
  if (c == 0){
    dout[(size_t)n_out*32 + row] = s;
    dout[(size_t)n_out*33 + row] = (target[row] != 0) ? 1.f : 0.f;
    dout[(size_t)n_out*34 + row] = km;
  }
}

extern "C" void kernel_launch(void* const* d_in, const int* in_sizes, int n_in,
                              void* d_out, int out_size, void* d_ws, size_t ws_size,
                              hipStream_t stream){
  const float* x      = (const float*)d_in[0];
  const float* W_up   = (const float*)d_in[1];
  const float* b_up   = (const float*)d_in[2];
  const float* W_conv = (const float*)d_in[3];
  const float* b_conv = (const float*)d_in[4];
  const float* Wb00   = (const float*)d_in[5];
  const float* bb00   = (const float*)d_in[6];
  const float* Wb01   = (const float*)d_in[7];
  const float* bb01   = (const float*)d_in[8];
  const float* Wb10   = (const float*)d_in[9];
  const float* bb10   = (const float*)d_in[10];
  const float* Wb11   = (const float*)d_in[11];
  const float* bb11   = (const float*)d_in[12];
  const float* Wb12   = (const float*)d_in[13];
  const float* bb12   = (const float*)d_in[14];
  const float* W_cls  = (const float*)d_in[15];
  const float* b_cls  = (const float*)d_in[16];
  const int*   nbr_in = (const int*)d_in[17];
  const int*   nbr_out= (const int*)d_in[18];
  const int*   target = (const int*)d_in[19];

  const int N = in_sizes[19];        // 65536
  const int P = in_sizes[17] / 27;
  const int pairsT = 27 * P;
  const int Nn = N / 8;              // 8192 parents

  int*   cnt  = (int*)d_ws;                          // N
  int*   rem  = cnt + N;                             // N*20
  float* wsf  = (float*)(rem + (size_t)N*20);
  float* f_tmp = wsf;                                // N*32
  float* f_out = f_tmp + (size_t)N*32;               // N*32
  float* a8    = f_out + (size_t)N*32;               // N*8
  float* b8    = a8 + (size_t)N*8;                   // N*8
  float* cls   = b8 + (size_t)N*8;                   // N
  float* pmax  = cls + N;                            // 256
  int*   pidx  = (int*)(pmax + 256);                 // 256
  float* gm    = pmax + 512;                         // [max, argmax]

  const int B = 256;

  k_rinit<<<cdiv(N,B),B,0,stream>>>(cnt, N);
  k_rbuild<<<cdiv((long long)pairsT,B),B,0,stream>>>(nbr_in, nbr_out, cnt, rem, P, N);

  k_up<<<Nn/32,512,0,stream>>>(x, W_up, b_up, f_tmp, Nn);

  k_conv1<<<dim3(Nn/32,2),512,0,stream>>>(f_tmp, W_conv, b_conv, cnt, rem, f_out, N);

  for (int l = 0; l < 3; ++l){
    k_blk_a<<<Nn/16,512,0,stream>>>(f_out, Wb00 + (size_t)l*6912, bb00 + l*8,
                                    Wb10 + (size_t)l*256, bb10 + l*8, cnt, rem, a8, b8, N);
    k_blk_b<<<N/128,512,0,stream>>>(a8, b8,
                                    Wb01 + (size_t)l*3456, bb01 + l*16,
                                    Wb11 + (size_t)l*1728, bb11 + l*8,
                                    Wb12 + (size_t)l*128, bb12 + l*16,
                                    cnt, rem, f_out, N);
  }

  k_cls<<<dim3(Nn/16,2),B,0,stream>>>(f_out, W_cls, b_cls, cnt, rem, cls, N);

  k_reduce1<<<256,256,0,stream>>>(cls, pmax, pidx, N);
  k_reduce2<<<1,256,0,stream>>>(pmax, pidx, gm, 256);

  k_final<<<cdiv((long long)N*32,B),B,0,stream>>>(f_out, cls, target, gm, (float*)d_out, N);
}

// Round 11
// 210.683 us; speedup vs baseline: 2.0300x; 2.0300x over previous
//
#include <hip/hip_runtime.h>
#include <math.h>

static inline int cdiv(long long a, int b){ return (int)((a + b - 1) / b); }
#define DEVINL __device__ __forceinline__

DEVINL float4 relu4(const float* a){
  return make_float4(fmaxf(a[0],0.f), fmaxf(a[1],0.f), fmaxf(a[2],0.f), fmaxf(a[3],0.f));
}

DEVINL void load32(float* fv, const float* __restrict__ p){
#pragma unroll
  for (int q = 0; q < 8; ++q){
    float4 v = ((const float4*)p)[q];
    fv[4*q]=v.x; fv[4*q+1]=v.y; fv[4*q+2]=v.z; fv[4*q+3]=v.w;
  }
}
DEVINL void load8(float* fv, const float* __restrict__ p){
#pragma unroll
  for (int q = 0; q < 2; ++q){
    float4 v = ((const float4*)p)[q];
    fv[4*q]=v.x; fv[4*q+1]=v.y; fv[4*q+2]=v.z; fv[4*q+3]=v.w;
  }
}

// tap index for sibling pair: d = o' - o componentwise; k = (dx+1)*9+(dy+1)*3+(dz+1)
DEVINL int sib_k(int o, int op){
  return 13 + 9*(((op>>2)&1) - ((o>>2)&1))
            + 3*(((op>>1)&1) - ((o>>1)&1))
            +   ((op&1) - (o&1));
}

// ---------- remainder list build: cross-parent valid neighbors only ----------
__global__ void k_rinit(int* __restrict__ cnt, int n){
  int i = blockIdx.x*blockDim.x + threadIdx.x;
  if (i < n) cnt[i] = 0;
}

__global__ void k_rbuild(const int* __restrict__ nin, const int* __restrict__ nout,
                         int* __restrict__ cnt, int* __restrict__ rem, int P, int N){
  int p = blockIdx.x*blockDim.x + threadIdx.x;
  if (p >= 27*P) return;
  int oi = nout[p];
  if (oi >= N) return;
  int j = nin[p];
  if ((oi >> 3) == (j >> 3)) return;
  int k = p / P;
  int pos = atomicAdd(&cnt[oi], 1);
  rem[(size_t)oi*20 + pos] = (j << 5) | k;
}

// ---------- up (r9/r10): R=4 parents/thread, wave=kk (uniform); grid Nn/32 ----------
__global__ __launch_bounds__(512) void k_up(const float* __restrict__ x,
    const float* __restrict__ Wup, const float* __restrict__ bup,
    float* __restrict__ f, int Nn){
  __shared__ float Ws[8*64*32];
  int t = threadIdx.x;
  for (int m = t; m < 4096; m += 512)
    ((float4*)Ws)[m] = ((const float4*)Wup)[m];
  __syncthreads();
  int kk = t >> 6;
  int lane = t & 63, nq = lane >> 3, cg = lane & 7;
  int n0 = blockIdx.x*32 + nq*4;
  int c0 = cg*4;
  const float* wk = Ws + kk*2048 + c0;
  float4 b4 = *(const float4*)(bup + c0);
  float acc[4][4];
#pragma unroll
  for (int i = 0; i < 4; ++i){ acc[i][0]=b4.x; acc[i][1]=b4.y; acc[i][2]=b4.z; acc[i][3]=b4.w; }
#pragma unroll
  for (int h = 0; h < 8; ++h){
    float fv[4][8];
#pragma unroll
    for (int i = 0; i < 4; ++i){
      float4 v0 = ((const float4*)(x + (size_t)(n0+i)*64))[h*2+0];
      float4 v1 = ((const float4*)(x + (size_t)(n0+i)*64))[h*2+1];
      fv[i][0]=v0.x; fv[i][1]=v0.y; fv[i][2]=v0.z; fv[i][3]=v0.w;
      fv[i][4]=v1.x; fv[i][5]=v1.y; fv[i][6]=v1.z; fv[i][7]=v1.w;
    }
#pragma unroll
    for (int cc = 0; cc < 8; ++cc){
      float4 w = *(const float4*)(wk + (h*8+cc)*32);
#pragma unroll
      for (int i = 0; i < 4; ++i){
        acc[i][0]=fmaf(fv[i][cc],w.x,acc[i][0]); acc[i][1]=fmaf(fv[i][cc],w.y,acc[i][1]);
        acc[i][2]=fmaf(fv[i][cc],w.z,acc[i][2]); acc[i][3]=fmaf(fv[i][cc],w.w,acc[i][3]);
      }
    }
  }
#pragma unroll
  for (int i = 0; i < 4; ++i)
    *(float4*)(f + ((size_t)(n0+i)*8 + kk)*32 + c0) = relu4(acc[i]);
}

// ---------- conv1 (r6 verbatim): 27x32x32, sibling-static; wave-uniform o; c-quarter ----------
// block 512 = 8 waves(=o) x [32 parents x 2 cg]; covers 256 rows x 8 outs. grid (N/256, 4)
__global__ __launch_bounds__(512) void k_conv1(const float* __restrict__ fin,
    const float* __restrict__ Wg, const float* __restrict__ bg,
    const int* __restrict__ cnt, const int* __restrict__ rem,
    float* __restrict__ fout, int N){
  __shared__ float Ws[27*32*8];       // [k][cc][8], 27.6 KB
  const int cb = blockIdx.y*8;
  int t = threadIdx.x;
  for (int m = t; m < 1728; m += 512){
    int k = m >> 6, r = m & 63, cc = r >> 1, q = r & 1;
    *(float4*)&Ws[k*256 + cc*8 + q*4] =
      *(const float4*)&Wg[((size_t)(k*32 + cc))*32 + cb + q*4];
  }
  __syncthreads();
  int o = t >> 6, lane = t & 63, p = lane >> 1, cg = lane & 1;
  int base = blockIdx.x*256 + p*8;
  int row = base + o, c0 = cg*4;
  float4 b4 = *(const float4*)(bg + cb + c0);
  float acc[4] = {b4.x,b4.y,b4.z,b4.w};
  float fv[32];
#pragma unroll
  for (int op = 0; op < 8; ++op){
    int kk = sib_k(o, op);            // wave-uniform
    load32(fv, fin + (size_t)(base+op)*32);
    const float* wk = Ws + kk*256 + c0;
#pragma unroll
    for (int cc = 0; cc < 32; ++cc){
      float4 w = *(const float4*)(wk + cc*8);
      acc[0]=fmaf(fv[cc],w.x,acc[0]); acc[1]=fmaf(fv[cc],w.y,acc[1]);
      acc[2]=fmaf(fv[cc],w.z,acc[2]); acc[3]=fmaf(fv[cc],w.w,acc[3]);
    }
  }
  int nrm = cnt[row];
  for (int s = 0; s < nrm; ++s){
    int e = rem[(size_t)row*20 + s];
    int kk = e & 31, j = e >> 5;
    load32(fv, fin + (size_t)j*32);
    const float* wk = Ws + kk*256 + c0;
#pragma unroll
    for (int cc = 0; cc < 32; ++cc){
      float4 w = *(const float4*)(wk + cc*8);
      acc[0]=fmaf(fv[cc],w.x,acc[0]); acc[1]=fmaf(fv[cc],w.y,acc[1]);
      acc[2]=fmaf(fv[cc],w.z,acc[2]); acc[3]=fmaf(fv[cc],w.w,acc[3]);
    }
  }
  *(float4*)(fout + (size_t)row*32 + cb + c0) = relu4(acc);
}

// ---------- blk_a (r10): a8 = relu(sconv32->8+b00); b8 = relu(f@W10+b10) ----------
// block 512 = 8 waves(=o) x [16 parents x 4 cg(2 outs)]; grid Nn/16 = 512 -> 16 waves/CU
__global__ __launch_bounds__(512) void k_blk_a(const float* __restrict__ fO,
    const float* __restrict__ W00, const float* __restrict__ b00,
    const float* __restrict__ W10, const float* __restrict__ b10,
    const int* __restrict__ cnt, const int* __restrict__ rem,
    float* __restrict__ a8, float* __restrict__ b8, int N){
  __shared__ float Ws[27*256 + 256];
  int t = threadIdx.x;
  for (int m = t; m < 1728; m += 512)
    ((float4*)Ws)[m] = ((const float4*)W00)[m];    // [kk][cc][8] native layout
  if (t < 64) *(float4*)&Ws[6912 + t*4] = ((const float4*)W10)[t];
  __syncthreads();
  int o = t >> 6, lane = t & 63;
  int p = lane >> 2, cg = lane & 3;
  int parent = blockIdx.x*16 + p;
  int base = parent*8, row = base + o;
  int c0 = cg*2;
  float acc[2] = {b00[c0], b00[c0+1]};
  float fv[32];
#pragma unroll 1
  for (int op = 0; op < 8; ++op){
    int kk = sib_k(o, op);                // wave-uniform
    load32(fv, fO + (size_t)(base+op)*32);
    const float* wk = Ws + kk*256 + c0;
#pragma unroll
    for (int cc = 0; cc < 32; ++cc){
      float2 w = *(const float2*)(wk + cc*8);
      acc[0]=fmaf(fv[cc],w.x,acc[0]); acc[1]=fmaf(fv[cc],w.y,acc[1]);
    }
  }
  int nrm = cnt[row];
  for (int s = 0; s < nrm; ++s){
    int e = rem[(size_t)row*20 + s];
    int kk = e & 31, j = e >> 5;
    load32(fv, fO + (size_t)j*32);
    const float* wk = Ws + kk*256 + c0;
#pragma unroll
    for (int cc = 0; cc < 32; ++cc){
      float2 w = *(const float2*)(wk + cc*8);
      acc[0]=fmaf(fv[cc],w.x,acc[0]); acc[1]=fmaf(fv[cc],w.y,acc[1]);
    }
  }
  *(float2*)(a8 + (size_t)row*8 + c0) = make_float2(fmaxf(acc[0],0.f), fmaxf(acc[1],0.f));
  // dense branch on own row
  load32(fv, fO + (size_t)row*32);
  float accb[2] = {b10[c0], b10[c0+1]};
#pragma unroll
  for (int cc = 0; cc < 32; ++cc){
    float2 w = *(const float2*)(Ws + 6912 + cc*8 + c0);
    accb[0]=fmaf(fv[cc],w.x,accb[0]); accb[1]=fmaf(fv[cc],w.y,accb[1]);
  }
  *(float2*)(b8 + (size_t)row*8 + c0) = make_float2(fmaxf(accb[0],0.f), fmaxf(accb[1],0.f));
}

// ---------- blk_b (r6): fout[:,0:16] += sconv8->16(a8)+b01 ;
//            fout[:,16:32] += relu(sconv8->8(b8)+b11)@W12+b12 ----------
// block 512 = 8 waves(=o) x [16 parents x 4 cg]; grid N/128 = 512
__global__ __launch_bounds__(512) void k_blk_b(const float* __restrict__ a8,
    const float* __restrict__ b8,
    const float* __restrict__ W01, const float* __restrict__ b01,
    const float* __restrict__ W11, const float* __restrict__ b11,
    const float* __restrict__ W12, const float* __restrict__ b12,
    const int* __restrict__ cnt, const int* __restrict__ rem,
    float* __restrict__ fout, int N){
  __shared__ float Ws[27*128 + 27*64 + 128];   // 3456 + 1728 + 128
  int t = threadIdx.x;
  for (int m = t; m < 864; m += 512)
    ((float4*)Ws)[m] = ((const float4*)W01)[m];
  for (int m = t; m < 432; m += 512)
    ((float4*)(Ws + 3456))[m] = ((const float4*)W11)[m];
  if (t < 32) *(float4*)&Ws[5184 + t*4] = ((const float4*)W12)[t];
  __syncthreads();
  int o = t >> 6, lane = t & 63, p = lane >> 2, cg = lane & 3;
  int base = blockIdx.x*128 + p*8;
  int row = base + o, c0 = cg*4;
  float4 b4 = *(const float4*)(b01 + c0);
  float acc0[4] = {b4.x,b4.y,b4.z,b4.w};
  float t8[8];
#pragma unroll
  for (int c = 0; c < 8; ++c) t8[c] = b11[c];
  float av[8], bv[8];
#pragma unroll
  for (int op = 0; op < 8; ++op){
    int kk = sib_k(o, op);
    load8(av, a8 + (size_t)(base+op)*8);
    load8(bv, b8 + (size_t)(base+op)*8);
    const float* w01k = Ws + kk*128 + c0;
    const float* w11k = Ws + 3456 + kk*64;
#pragma unroll
    for (int cc = 0; cc < 8; ++cc){
      float4 w = *(const float4*)(w01k + cc*16);
      acc0[0]=fmaf(av[cc],w.x,acc0[0]); acc0[1]=fmaf(av[cc],w.y,acc0[1]);
      acc0[2]=fmaf(av[cc],w.z,acc0[2]); acc0[3]=fmaf(av[cc],w.w,acc0[3]);
      float4 u0 = *(const float4*)(w11k + cc*8);
      float4 u1 = *(const float4*)(w11k + cc*8 + 4);
      t8[0]=fmaf(bv[cc],u0.x,t8[0]); t8[1]=fmaf(bv[cc],u0.y,t8[1]);
      t8[2]=fmaf(bv[cc],u0.z,t8[2]); t8[3]=fmaf(bv[cc],u0.w,t8[3]);
      t8[4]=fmaf(bv[cc],u1.x,t8[4]); t8[5]=fmaf(bv[cc],u1.y,t8[5]);
      t8[6]=fmaf(bv[cc],u1.z,t8[6]); t8[7]=fmaf(bv[cc],u1.w,t8[7]);
    }
  }
  int nrm = cnt[row];
  for (int s = 0; s < nrm; ++s){
    int e = rem[(size_t)row*20 + s];
    int kk = e & 31, j = e >> 5;
    load8(av, a8 + (size_t)j*8);
    load8(bv, b8 + (size_t)j*8);
    const float* w01k = Ws + kk*128 + c0;
    const float* w11k = Ws + 3456 + kk*64;
#pragma unroll
    for (int cc = 0; cc < 8; ++cc){
      float4 w = *(const float4*)(w01k + cc*16);
      acc0[0]=fmaf(av[cc],w.x,acc0[0]); acc0[1]=fmaf(av[cc],w.y,acc0[1]);
      acc0[2]=fmaf(av[cc],w.z,acc0[2]); acc0[3]=fmaf(av[cc],w.w,acc0[3]);
      float4 u0 = *(const float4*)(w11k + cc*8);
      float4 u1 = *(const float4*)(w11k + cc*8 + 4);
      t8[0]=fmaf(bv[cc],u0.x,t8[0]); t8[1]=fmaf(bv[cc],u0.y,t8[1]);
      t8[2]=fmaf(bv[cc],u0.z,t8[2]); t8[3]=fmaf(bv[cc],u0.w,t8[3]);
      t8[4]=fmaf(bv[cc],u1.x,t8[4]); t8[5]=fmaf(bv[cc],u1.y,t8[5]);
      t8[6]=fmaf(bv[cc],u1.z,t8[6]); t8[7]=fmaf(bv[cc],u1.w,t8[7]);
    }
  }
#pragma unroll
  for (int c = 0; c < 8; ++c) t8[c] = fmaxf(t8[c], 0.f);
  float4 d4 = *(const float4*)(b12 + c0);
  float acc1[4] = {d4.x,d4.y,d4.z,d4.w};
#pragma unroll
  for (int cc = 0; cc < 8; ++cc){
    float4 w = *(const float4*)(Ws + 5184 + cc*16 + c0);
    acc1[0]=fmaf(t8[cc],w.x,acc1[0]); acc1[1]=fmaf(t8[cc],w.y,acc1[1]);
    acc1[2]=fmaf(t8[cc],w.z,acc1[2]); acc1[3]=fmaf(t8[cc],w.w,acc1[3]);
  }
  float4* o0 = (float4*)(fout + (size_t)row*32 + c0);
  float4* o1 = (float4*)(fout + (size_t)row*32 + 16 + c0);
  float4 v0 = *o0, v1 = *o1;
  v0.x+=acc0[0]; v0.y+=acc0[1]; v0.z+=acc0[2]; v0.w+=acc0[3];
  v1.x+=acc1[0]; v1.y+=acc1[1]; v1.z+=acc1[2]; v1.w+=acc1[3];
  *o0 = v0; *o1 = v1;
}

// ---------- cls (r10): 32->1 conv; c-quarter split + shuffle reduce ----------
// block 256 = 4 waves(o = by*4+w) x [16 parents x 4 q]; grid (Nn/16, 2) = 1024 blocks
__global__ __launch_bounds__(256) void k_cls(const float* __restrict__ fO,
    const float* __restrict__ Wc, const float* __restrict__ bc,
    const int* __restrict__ cnt, const int* __restrict__ rem,
    float* __restrict__ cls, int N){
  __shared__ float Ws[27*32];
  int t = threadIdx.x;
  if (t < 216) ((float4*)Ws)[t] = ((const float4*)Wc)[t];
  __syncthreads();
  int o = blockIdx.y*4 + (t >> 6);
  int lane = t & 63, p = lane >> 2, q = lane & 3;
  int base = (blockIdx.x*16 + p)*8;
  int row = base + o;
  float acc = 0.f;
#pragma unroll 1
  for (int op = 0; op < 8; ++op){
    int kk = sib_k(o, op);
    const float4* fp = (const float4*)(fO + (size_t)(base+op)*32 + q*8);
    float4 v0 = fp[0], v1 = fp[1];
    const float4* wp = (const float4*)(Ws + kk*32 + q*8);
    float4 w0 = wp[0], w1 = wp[1];
    acc = fmaf(v0.x,w0.x,acc); acc = fmaf(v0.y,w0.y,acc);
    acc = fmaf(v0.z,w0.z,acc); acc = fmaf(v0.w,w0.w,acc);
    acc = fmaf(v1.x,w1.x,acc); acc = fmaf(v1.y,w1.y,acc);
    acc = fmaf(v1.z,w1.z,acc); acc = fmaf(v1.w,w1.w,acc);
  }
  int nrm = cnt[row];
  for (int s = 0; s < nrm; ++s){
    int e = rem[(size_t)row*20 + s];
    int kk = e & 31, j = e >> 5;
    const float4* fp = (const float4*)(fO + (size_t)j*32 + q*8);
    float4 v0 = fp[0], v1 = fp[1];
    const float4* wp = (const float4*)(Ws + kk*32 + q*8);
    float4 w0 = wp[0], w1 = wp[1];
    acc = fmaf(v0.x,w0.x,acc); acc = fmaf(v0.y,w0.y,acc);
    acc = fmaf(v0.z,w0.z,acc); acc = fmaf(v0.w,w0.w,acc);
    acc = fmaf(v1.x,w1.x,acc); acc = fmaf(v1.y,w1.y,acc);
    acc = fmaf(v1.z,w1.z,acc); acc = fmaf(v1.w,w1.w,acc);
  }
  acc += __shfl_xor(acc, 1);
  acc += __shfl_xor(acc, 2);
  if (q == 0) cls[row] = acc + bc[0];
}

// ---------- max/argmax (first-index tie-break) ----------
__global__ void k_reduce1(const float* __restrict__ s, float* __restrict__ pmax,
                          int* __restrict__ pidx, int n){
  __shared__ float sm[256]; __shared__ int si[256];
  int t = threadIdx.x;
  float v = -INFINITY; int vi = 0x7fffffff;
  for (int j = blockIdx.x*256 + t; j < n; j += gridDim.x*256){
    float w = s[j];
    if (w > v){ v = w; vi = j; }
  }
  sm[t] = v; si[t] = vi; __syncthreads();
  for (int o = 128; o > 0; o >>= 1){
    if (t < o){
      if (sm[t+o] > sm[t] || (sm[t+o] == sm[t] && si[t+o] < si[t])){ sm[t]=sm[t+o]; si[t]=si[t+o]; }
    }
    __syncthreads();
  }
  if (t == 0){ pmax[blockIdx.x] = sm[0]; pidx[blockIdx.x] = si[0]; }
}

__global__ void k_reduce2(const float* __restrict__ pmax, const int* __restrict__ pidx,
                          float* __restrict__ g, int nb){
  __shared__ float sm[256]; __shared__ int si[256];
  int t = threadIdx.x;
  sm[t] = (t < nb) ? pmax[t] : -INFINITY;
  si[t] = (t < nb) ? pidx[t] : 0x7fffffff;
  __syncthreads();
  for (int o = 128; o > 0; o >>= 1){
    if (t < o){
      if (sm[t+o] > sm[t] || (sm[t+o] == sm[t] && si[t+o] < si[t])){ sm[t]=sm[t+o]; si[t]=si[t+o]; }
    }
    __syncthreads();
  }
  if (t == 0){ g[0] = sm[0]; ((int*)g)[1] = si[0]; }
}

// ---------- finalize ----------
__global__ void k_final(const float* __restrict__ out, const float* __restrict__ cls,
                        const int* __restrict__ target, const float* __restrict__ g,
                        float* __restrict__ dout, int n_out){
  int idx = blockIdx.x*blockDim.x + threadIdx.x;
  if (idx >= n_out*32) return;
  int row = idx >> 5, c = idx & 31;
  float s = cls[row];
  bool keep = s > 0.f;
  if (g[0] < 0.f) keep = keep || (row == ((const int*)g)[1]);
  float km = keep ? 1.f : 0.f;
  dout[idx] = out[idx] * km;
  if (c == 0){
    dout[(size_t)n_out*32 + row] = s;
    dout[(size_t)n_out*33 + row] = (target[row] != 0) ? 1.f : 0.f;
    dout[(size_t)n_out*34 + row] = km;
  }
}

extern "C" void kernel_launch(void* const* d_in, const int* in_sizes, int n_in,
                              void* d_out, int out_size, void* d_ws, size_t ws_size,
                              hipStream_t stream){
  const float* x      = (const float*)d_in[0];
  const float* W_up   = (const float*)d_in[1];
  const float* b_up   = (const float*)d_in[2];
  const float* W_conv = (const float*)d_in[3];
  const float* b_conv = (const float*)d_in[4];
  const float* Wb00   = (const float*)d_in[5];
  const float* bb00   = (const float*)d_in[6];
  const float* Wb01   = (const float*)d_in[7];
  const float* bb01   = (const float*)d_in[8];
  const float* Wb10   = (const float*)d_in[9];
  const float* bb10   = (const float*)d_in[10];
  const float* Wb11   = (const float*)d_in[11];
  const float* bb11   = (const float*)d_in[12];
  const float* Wb12   = (const float*)d_in[13];
  const float* bb12   = (const float*)d_in[14];
  const float* W_cls  = (const float*)d_in[15];
  const float* b_cls  = (const float*)d_in[16];
  const int*   nbr_in = (const int*)d_in[17];
  const int*   nbr_out= (const int*)d_in[18];
  const int*   target = (const int*)d_in[19];

  const int N = in_sizes[19];        // 65536
  const int P = in_sizes[17] / 27;
  const int pairsT = 27 * P;
  const int Nn = N / 8;              // 8192 parents

  int*   cnt  = (int*)d_ws;                          // N
  int*   rem  = cnt + N;                             // N*20
  float* wsf  = (float*)(rem + (size_t)N*20);
  float* f_tmp = wsf;                                // N*32
  float* f_out = f_tmp + (size_t)N*32;               // N*32
  float* a8    = f_out + (size_t)N*32;               // N*8
  float* b8    = a8 + (size_t)N*8;                   // N*8
  float* cls   = b8 + (size_t)N*8;                   // N
  float* pmax  = cls + N;                            // 256
  int*   pidx  = (int*)(pmax + 256);                 // 256
  float* gm    = pmax + 512;                         // [max, argmax]

  const int B = 256;

  k_rinit<<<cdiv(N,B),B,0,stream>>>(cnt, N);
  k_rbuild<<<cdiv((long long)pairsT,B),B,0,stream>>>(nbr_in, nbr_out, cnt, rem, P, N);

  k_up<<<Nn/32,512,0,stream>>>(x, W_up, b_up, f_tmp, Nn);

  k_conv1<<<dim3(N/256,4),512,0,stream>>>(f_tmp, W_conv, b_conv, cnt, rem, f_out, N);

  for (int l = 0; l < 3; ++l){
    k_blk_a<<<Nn/16,512,0,stream>>>(f_out, Wb00 + (size_t)l*6912, bb00 + l*8,
                                    Wb10 + (size_t)l*256, bb10 + l*8, cnt, rem, a8, b8, N);
    k_blk_b<<<N/128,512,0,stream>>>(a8, b8,
                                    Wb01 + (size_t)l*3456, bb01 + l*16,
                                    Wb11 + (size_t)l*1728, bb11 + l*8,
                                    Wb12 + (size_t)l*128, bb12 + l*16,
                                    cnt, rem, f_out, N);
  }

  k_cls<<<dim3(Nn/16,2),B,0,stream>>>(f_out, W_cls, b_cls, cnt, rem, cls, N);

  k_reduce1<<<256,256,0,stream>>>(cls, pmax, pidx, N);
  k_reduce2<<<1,256,0,stream>>>(pmax, pidx, gm, 256);

  k_final<<<cdiv((long long)N*32,B),B,0,stream>>>(f_out, cls, target, gm, (float*)d_out, N);
}